// Round 5
// baseline (2566.390 us; speedup 1.0000x reference)
//
#include <hip/hip_runtime.h>
#include <hip/hip_bf16.h>

// LCA layer on MI355X — rank-factored steps, 32x32x16 MFMA, vectorized epilogue.
//   b = x@W ; g[j] = sum_k W[k][j]^2
//   u1 = 0.1 b ; a1 = relu(u1 - 0.1)
//   per step: t = a@W^T ; s = t@W ; u' = 0.9u + 0.1b - 0.1s + 0.1*a*g ; a' = relu(u'-0.1)
//   out = a@W^T (fp32)
// GEMM core: 128x128 tile, 4 waves 2x2, wave = 64x64 via 2x2 mfma_32x32x16_bf16
// (half the MFMA issue slots of 16x16x32 for the same work), OPERAND SWAP so a
// lane's reg-quad = 4 consecutive output cols at one row (8B/16B vector epilogue),
// BK=64 as two BK=32 LDS planes, global_load_lds width-16, Bt ([N][K]) layout.

typedef __bf16 bf16_t;
typedef __bf16 bf16x8 __attribute__((ext_vector_type(8)));
typedef __bf16 bf16x4 __attribute__((ext_vector_type(4)));
typedef float  f32x4  __attribute__((ext_vector_type(4)));
typedef float  f32x16 __attribute__((ext_vector_type(16)));

__device__ __forceinline__ void g2lds16(const void* g, void* l) {
    __builtin_amdgcn_global_load_lds(
        (const __attribute__((address_space(1))) void*)g,
        (__attribute__((address_space(3))) void*)l,
        16, 0, 0);
}

enum { MODE_B = 0, MODE_T = 1, MODE_STEP2 = 2, MODE_OUT = 3 };

// C[m][n] = sum_k A[m][k] * Bt[n][k]  (A:[M][K], Bt:[N][K], bf16, K%64==0,
// grid covers M,N in 128-tiles). 256 thr = 4 waves 2x2; wave = 64x64.
template<int MODE>
__global__ __launch_bounds__(256)
void gemm_bt(const bf16_t* __restrict__ A, const bf16_t* __restrict__ Bt,
             int N, int K,
             float*  __restrict__ outF,   // MODE_OUT: final fp32 output
             bf16_t* __restrict__ outH,   // MODE_T: t ; MODE_B/STEP2: a
             bf16_t* __restrict__ bb,     // MODE_B: write b ; MODE_STEP2: read b
             bf16_t* __restrict__ u,      // MODE_B: write u ; MODE_STEP2: rmw u
             const float* __restrict__ g) // MODE_STEP2: diag(W^T W), [N]
{
    // two BK=32 planes per operand: As[2][128][32], Bs[2][128][32]
    __shared__ __attribute__((aligned(16))) bf16_t As[2 * 128 * 32];
    __shared__ __attribute__((aligned(16))) bf16_t Bs[2 * 128 * 32];

    const int t  = threadIdx.x;
    const int l  = t & 63;
    const int w  = t >> 6;
    const int wm = (w >> 1) * 64;
    const int wn = (w & 1) * 64;

    const int rowA = blockIdx.y * 128;
    const int colB = blockIdx.x * 128;

    // staging (per plane = m97 BK=32 pattern): thread t loads 16B for rows
    // t/4 and 64+t/4 at k-offset (t&3)*8 within the plane.
    const int srow = t >> 2;
    const int skc  = (t & 3) * 8;
    const bf16_t* gA = A  + (size_t)(rowA + srow) * K + skc;
    const bf16_t* gB = Bt + (size_t)(colB + srow) * K + skc;
    const size_t half = (size_t)64 * K;
    char* lA = (char*)As + t * 16;
    char* lB = (char*)Bs + t * 16;

    f32x16 acc[2][2];
#pragma unroll
    for (int i = 0; i < 2; ++i)
#pragma unroll
        for (int j = 0; j < 2; ++j)
#pragma unroll
            for (int r = 0; r < 16; ++r) acc[i][j][r] = 0.f;

    // 32x32x16 A/B fragment: lane l -> row (l&31), k (l>>5)*8 .. +7 (16B contig)
    const int lr = l & 31;
    const int lc = (l >> 5) * 8;
    const bf16_t* pA = As + (wm + lr) * 32 + lc;
    const bf16_t* pB = Bs + (wn + lr) * 32 + lc;

    for (int k0 = 0; k0 < K; k0 += 64) {
        // plane 0 = k0..k0+31, plane 1 = k0+32..k0+63
        g2lds16(gA + k0,             lA);
        g2lds16(gA + k0 + half,      lA + 4096);
        g2lds16(gA + k0 + 32,        lA + 8192);
        g2lds16(gA + k0 + 32 + half, lA + 12288);
        g2lds16(gB + k0,             lB);
        g2lds16(gB + k0 + half,      lB + 4096);
        g2lds16(gB + k0 + 32,        lB + 8192);
        g2lds16(gB + k0 + 32 + half, lB + 12288);
        __syncthreads();   // vmcnt(0) drained before barrier -> LDS ready

        // 4 chunks of K=16: pc>>1 = plane, pc&1 = 16-chunk within plane
#pragma unroll
        for (int pc = 0; pc < 4; ++pc) {
            const bf16_t* qA = pA + (pc >> 1) * 4096 + (pc & 1) * 16;
            const bf16_t* qB = pB + (pc >> 1) * 4096 + (pc & 1) * 16;
            bf16x8 af[2], bfr[2];
            af[0]  = *(const bf16x8*)(qA);
            af[1]  = *(const bf16x8*)(qA + 32 * 32);
            bfr[0] = *(const bf16x8*)(qB);
            bfr[1] = *(const bf16x8*)(qB + 32 * 32);
            // OPERAND SWAP: (b_frag, a_frag) -> lane holds
            // C[m = wm+32i+(l&31)][n = wn+32j+4*(l>>5)+8*(reg>>2)+(reg&3)]
#pragma unroll
            for (int i = 0; i < 2; ++i)
#pragma unroll
                for (int j = 0; j < 2; ++j)
                    acc[i][j] = __builtin_amdgcn_mfma_f32_32x32x16_bf16(
                        bfr[j], af[i], acc[i][j], 0, 0, 0);
        }
        __syncthreads();
    }

    // epilogue (swapped 32x32 layout): m = rowA+wm+32i+(l&31),
    // n = colB+wn+32j+4*(l>>5)+8*rg + (0..3), rg = reg>>2
    const int m0 = rowA + wm + (l & 31);
    const int n0 = colB + wn + ((l >> 5) * 4);

    f32x4 gvv[2][4];
    if (MODE == MODE_STEP2) {
#pragma unroll
        for (int j = 0; j < 2; ++j)
#pragma unroll
            for (int rg = 0; rg < 4; ++rg)
                gvv[j][rg] = *(const f32x4*)(g + n0 + j * 32 + rg * 8);
    }

#pragma unroll
    for (int i = 0; i < 2; ++i) {
        const int m = m0 + i * 32;
#pragma unroll
        for (int j = 0; j < 2; ++j) {
#pragma unroll
            for (int rg = 0; rg < 4; ++rg) {
                const size_t idx = (size_t)m * N + (n0 + j * 32 + rg * 8);
                const f32x4 c = { acc[i][j][rg * 4 + 0], acc[i][j][rg * 4 + 1],
                                  acc[i][j][rg * 4 + 2], acc[i][j][rg * 4 + 3] };
                if (MODE == MODE_T) {
                    bf16x4 o;
#pragma unroll
                    for (int r = 0; r < 4; ++r) o[r] = (bf16_t)c[r];
                    *(bf16x4*)(outH + idx) = o;
                } else if (MODE == MODE_B) {
                    bf16x4 ob, ou, oa;
#pragma unroll
                    for (int r = 0; r < 4; ++r) {
                        const float un = 0.1f * c[r];   // u1 = 0.1 b (u0=0 => a0=0)
                        ob[r] = (bf16_t)c[r];
                        ou[r] = (bf16_t)un;
                        oa[r] = (bf16_t)fmaxf(un - 0.1f, 0.f);
                    }
                    *(bf16x4*)(bb   + idx) = ob;
                    *(bf16x4*)(u    + idx) = ou;
                    *(bf16x4*)(outH + idx) = oa;
                } else if (MODE == MODE_STEP2) {
                    const bf16x4 uv = *(const bf16x4*)(u  + idx);
                    const bf16x4 bv = *(const bf16x4*)(bb + idx);
                    bf16x4 ou, oa;
#pragma unroll
                    for (int r = 0; r < 4; ++r) {
                        const float uo = (float)uv[r];
                        const float ao = fmaxf(uo - 0.1f, 0.f);   // a_old from u_old
                        const float un = 0.9f * uo + 0.1f * (float)bv[r]
                                       - 0.1f * c[r] + 0.1f * ao * gvv[j][rg][r];
                        ou[r] = (bf16_t)un;
                        oa[r] = (bf16_t)fmaxf(un - 0.1f, 0.f);    // a_next (no race)
                    }
                    *(bf16x4*)(u    + idx) = ou;
                    *(bf16x4*)(outH + idx) = oa;
                } else { // MODE_OUT
                    *(f32x4*)(outF + idx) = c;
                }
            }
        }
    }
}

__global__ void cast_x_kernel(const float* __restrict__ x, bf16_t* __restrict__ xh, int n) {
    int i = blockIdx.x * 256 + threadIdx.x;
    if (i < n) xh[i] = (bf16_t)x[i];
}

// Wh = bf16(W) [1024][4096] ; WT = bf16(W^T) [4096][1024]
__global__ void prep_w_kernel(const float* __restrict__ W,
                              bf16_t* __restrict__ Wh, bf16_t* __restrict__ WT) {
    int i = blockIdx.x * 256 + threadIdx.x;
    if (i < 1024 * 4096) {
        int k = i >> 12;
        int n = i & 4095;
        bf16_t v = (bf16_t)W[i];
        Wh[i] = v;
        WT[(size_t)n * 1024 + k] = v;
    }
}

// g[j] = sum_k W[k][j]^2
__global__ void prep_g_kernel(const float* __restrict__ W, float* __restrict__ g) {
    int j = blockIdx.x * 256 + threadIdx.x;
    if (j < 4096) {
        float s = 0.f;
        for (int k = 0; k < 1024; ++k) {
            float v = W[(size_t)k * 4096 + j];
            s += v * v;
        }
        g[j] = s;
    }
}

extern "C" void kernel_launch(void* const* d_in, const int* in_sizes, int n_in,
                              void* d_out, int out_size, void* d_ws, size_t ws_size,
                              hipStream_t stream)
{
    const float* x = (const float*)d_in[0];   // [8192][1024]
    const float* W = (const float*)d_in[1];   // [1024][4096]

    // d_out doubles as scratch until the final GEMM writes it:
    //   [0,16MiB): xh (bf16 x) until b-GEMM, then t ; [16MiB,+16KiB): g
    bf16_t* xh = (bf16_t*)d_out;
    bf16_t* tt = (bf16_t*)d_out;
    float*  gd = (float*)((char*)d_out + 16777216);

    char* ws = (char*)d_ws;                   // 208 MiB total (proven footprint)
    bf16_t* a  = (bf16_t*)(ws);               //  64 MiB [8192][4096]
    bf16_t* bb = (bf16_t*)(ws + 67108864);    //  64 MiB [8192][4096]
    bf16_t* u  = (bf16_t*)(ws + 134217728);   //  64 MiB [8192][4096]
    bf16_t* Wh = (bf16_t*)(ws + 201326592);   //   8 MiB [1024][4096]
    bf16_t* WT = (bf16_t*)(ws + 209715200);   //   8 MiB [4096][1024]

    cast_x_kernel<<<8388608 / 256, 256, 0, stream>>>(x, xh, 8388608);
    prep_w_kernel<<<4194304 / 256, 256, 0, stream>>>(W, Wh, WT);
    prep_g_kernel<<<16, 256, 0, stream>>>(W, gd);

    // b = x@W ; u1 = 0.1b ; a1 = relu(u1-0.1).  A=xh, Bt=WT, N=4096, K=1024
    gemm_bt<MODE_B><<<dim3(32, 64), 256, 0, stream>>>(xh, WT, 4096, 1024,
                                                      nullptr, a, bb, u, nullptr);
    // 9 remaining steps: t = a@W^T (N=1024,K=4096) ; s = t@W fused u/a update
    for (int s = 0; s < 9; ++s) {
        gemm_bt<MODE_T><<<dim3(8, 64), 256, 0, stream>>>(a, Wh, 1024, 4096,
                                                         nullptr, tt, nullptr, nullptr, nullptr);
        gemm_bt<MODE_STEP2><<<dim3(32, 64), 256, 0, stream>>>(tt, WT, 4096, 1024,
                                                              nullptr, a, bb, u, gd);
    }
    // out = a@W^T : A=a, Bt=Wh, N=1024, K=4096, fp32 into d_out
    gemm_bt<MODE_OUT><<<dim3(8, 64), 256, 0, stream>>>(a, Wh, 1024, 4096,
                                                       (float*)d_out, nullptr, nullptr, nullptr, nullptr);
}

// Round 6
// 2080.432 us; speedup vs baseline: 1.2336x; 1.2336x over previous
//
#include <hip/hip_runtime.h>
#include <hip/hip_bf16.h>

// LCA layer on MI355X — rank-factored steps, 16x16x32 MFMA, vectorized epilogue.
//   b = x@W ; g[j] = sum_k W[k][j]^2
//   u1 = 0.1 b ; a1 = relu(u1 - 0.1)
//   per step: t = a@W^T ; s = t@W ; u' = 0.9u + 0.1b - 0.1s + 0.1*a*g ; a' = relu(u'-0.1)
//   out = a@W^T (fp32)
// GEMM core: BMx128 tile (BM=128: 4 waves 2x2; BM=256: 8 waves 4x2), wave = 64x64
// via 4x4 mfma_16x16x32_bf16 (bank-optimal LDS read pattern — 32x32 shape regressed
// 3x on SQ_LDS_BANK_CONFLICT), OPERAND SWAP so a lane's 4 acc regs = 4 consecutive
// output cols at one row (8B/16B vector epilogue), BK=64 as two BK=32 LDS planes,
// global_load_lds width-16, Bt ([N][K]) operand layout.

typedef __bf16 bf16_t;
typedef __bf16 bf16x8 __attribute__((ext_vector_type(8)));
typedef __bf16 bf16x4 __attribute__((ext_vector_type(4)));
typedef float  f32x4  __attribute__((ext_vector_type(4)));

__device__ __forceinline__ void g2lds16(const void* g, void* l) {
    __builtin_amdgcn_global_load_lds(
        (const __attribute__((address_space(1))) void*)g,
        (__attribute__((address_space(3))) void*)l,
        16, 0, 0);
}

enum { MODE_B = 0, MODE_T = 1, MODE_STEP2 = 2, MODE_OUT = 3 };

// C[m][n] = sum_k A[m][k] * Bt[n][k]  (A:[M][K], Bt:[N][K], bf16, K%64==0,
// grid covers M in BM-tiles, N in 128-tiles).
template<int MODE, int BM>
__global__ __launch_bounds__((BM == 256) ? 512 : 256)
void gemm_bt(const bf16_t* __restrict__ A, const bf16_t* __restrict__ Bt,
             int N, int K,
             float*  __restrict__ outF,   // MODE_OUT: final fp32 output
             bf16_t* __restrict__ outH,   // MODE_T: t ; MODE_B/STEP2: a
             bf16_t* __restrict__ bb,     // MODE_B: write b ; MODE_STEP2: read b
             bf16_t* __restrict__ u,      // MODE_B: write u ; MODE_STEP2: rmw u
             const float* __restrict__ g) // MODE_STEP2: diag(W^T W), [N]
{
    constexpr int NT  = (BM == 256) ? 512 : 256;  // threads per block
    constexpr int RPI = NT / 4;                    // rows per g2lds issue (A)

    // two BK=32 planes per operand
    __shared__ __attribute__((aligned(16))) bf16_t As[2 * BM * 32];
    __shared__ __attribute__((aligned(16))) bf16_t Bs[2 * 128 * 32];

    const int t  = threadIdx.x;
    const int l  = t & 63;
    const int w  = t >> 6;                 // BM=128: 0..3 (2x2); BM=256: 0..7 (4x2)
    const int wm = (w >> 1) * 64;
    const int wn = (w & 1) * 64;

    const int rowA = blockIdx.y * BM;
    const int colB = blockIdx.x * 128;

    // staging: thread t loads 16B for row t/4 (+RPI for 2nd issue) at k-offset (t&3)*8
    const int srow = t >> 2;               // 0..RPI-1
    const int skc  = (t & 3) * 8;
    const bf16_t* gA = A  + (size_t)(rowA + srow) * K + skc;
    const bf16_t* gB = Bt + (size_t)(colB + srow) * K + skc;
    const size_t halfA = (size_t)RPI * K;
    char* lA = (char*)As + t * 16;
    char* lB = (char*)Bs + t * 16;

    f32x4 acc[4][4];
#pragma unroll
    for (int i = 0; i < 4; ++i)
#pragma unroll
        for (int j = 0; j < 4; ++j)
#pragma unroll
            for (int r = 0; r < 4; ++r) acc[i][j][r] = 0.f;

    // fragment read: lane l -> index (l&15), k (l>>4)*8 .. +7 (16B contiguous)
    const int lrow = l & 15;
    const int lk   = (l >> 4) * 8;
    const bf16_t* pA = As + (wm + lrow) * 32 + lk;
    const bf16_t* pB = Bs + (wn + lrow) * 32 + lk;

    for (int k0 = 0; k0 < K; k0 += 64) {
#pragma unroll
        for (int p = 0; p < 2; ++p) {      // plane p covers k0+p*32 .. +31
            const int kp = k0 + p * 32;
            g2lds16(gA + kp,         lA + p * (BM * 64));
            g2lds16(gA + kp + halfA, lA + p * (BM * 64) + RPI * 64);
            if (NT == 512) {
                g2lds16(gB + kp, lB + p * 8192);           // 512 thr cover 128 rows
            } else {
                g2lds16(gB + kp,                  lB + p * 8192);
                g2lds16(gB + kp + (size_t)64 * K, lB + p * 8192 + 4096);
            }
        }
        __syncthreads();   // vmcnt(0) drained before barrier -> LDS ready

#pragma unroll
        for (int p = 0; p < 2; ++p) {
            const bf16_t* qA = pA + p * (BM * 32);
            const bf16_t* qB = pB + p * 4096;
            bf16x8 af[4], bfr[4];
#pragma unroll
            for (int i = 0; i < 4; ++i) af[i]  = *(const bf16x8*)(qA + i * 16 * 32);
#pragma unroll
            for (int j = 0; j < 4; ++j) bfr[j] = *(const bf16x8*)(qB + j * 16 * 32);
            // OPERAND SWAP: (b_frag, a_frag) -> lane holds
            // C[m = wm+i*16+(l&15)][n = wn+j*16+(l>>4)*4 + r], r = 0..3 contiguous.
#pragma unroll
            for (int i = 0; i < 4; ++i)
#pragma unroll
                for (int j = 0; j < 4; ++j)
                    acc[i][j] = __builtin_amdgcn_mfma_f32_16x16x32_bf16(
                        bfr[j], af[i], acc[i][j], 0, 0, 0);
        }
        __syncthreads();
    }

    // epilogue (swapped layout): m = rowA+wm+i*16+(l&15), n = colB+wn+j*16+(l>>4)*4+r
    const int m0 = rowA + wm + (l & 15);
    const int n0 = colB + wn + ((l >> 4) * 4);

    f32x4 gvv[4];
    if (MODE == MODE_STEP2) {
#pragma unroll
        for (int j = 0; j < 4; ++j) gvv[j] = *(const f32x4*)(g + n0 + j * 16);
    }

#pragma unroll
    for (int i = 0; i < 4; ++i) {
        const int m = m0 + i * 16;
#pragma unroll
        for (int j = 0; j < 4; ++j) {
            const size_t idx = (size_t)m * N + (n0 + j * 16);
            const f32x4 c = acc[i][j];
            if (MODE == MODE_T) {
                bf16x4 o;
#pragma unroll
                for (int r = 0; r < 4; ++r) o[r] = (bf16_t)c[r];
                *(bf16x4*)(outH + idx) = o;
            } else if (MODE == MODE_B) {
                bf16x4 ob, ou, oa;
#pragma unroll
                for (int r = 0; r < 4; ++r) {
                    const float un = 0.1f * c[r];       // u1 = 0.1 b (u0=0 => a0=0)
                    ob[r] = (bf16_t)c[r];
                    ou[r] = (bf16_t)un;
                    oa[r] = (bf16_t)fmaxf(un - 0.1f, 0.f);
                }
                *(bf16x4*)(bb   + idx) = ob;
                *(bf16x4*)(u    + idx) = ou;
                *(bf16x4*)(outH + idx) = oa;
            } else if (MODE == MODE_STEP2) {
                const bf16x4 uv = *(const bf16x4*)(u  + idx);
                const bf16x4 bv = *(const bf16x4*)(bb + idx);
                bf16x4 ou, oa;
#pragma unroll
                for (int r = 0; r < 4; ++r) {
                    const float uo = (float)uv[r];
                    const float ao = fmaxf(uo - 0.1f, 0.f);    // a_old from u_old
                    const float un = 0.9f * uo + 0.1f * (float)bv[r]
                                   - 0.1f * c[r] + 0.1f * ao * gvv[j][r];
                    ou[r] = (bf16_t)un;
                    oa[r] = (bf16_t)fmaxf(un - 0.1f, 0.f);     // a_next (no race)
                }
                *(bf16x4*)(u    + idx) = ou;
                *(bf16x4*)(outH + idx) = oa;
            } else { // MODE_OUT
                *(f32x4*)(outF + idx) = c;
            }
        }
    }
}

__global__ void cast_x_kernel(const float* __restrict__ x, bf16_t* __restrict__ xh, int n) {
    int i = blockIdx.x * 256 + threadIdx.x;
    if (i < n) xh[i] = (bf16_t)x[i];
}

// Wh = bf16(W) [1024][4096] ; WT = bf16(W^T) [4096][1024]
__global__ void prep_w_kernel(const float* __restrict__ W,
                              bf16_t* __restrict__ Wh, bf16_t* __restrict__ WT) {
    int i = blockIdx.x * 256 + threadIdx.x;
    if (i < 1024 * 4096) {
        int k = i >> 12;
        int n = i & 4095;
        bf16_t v = (bf16_t)W[i];
        Wh[i] = v;
        WT[(size_t)n * 1024 + k] = v;
    }
}

// g[j] = sum_k W[k][j]^2
__global__ void prep_g_kernel(const float* __restrict__ W, float* __restrict__ g) {
    int j = blockIdx.x * 256 + threadIdx.x;
    if (j < 4096) {
        float s = 0.f;
        for (int k = 0; k < 1024; ++k) {
            float v = W[(size_t)k * 4096 + j];
            s += v * v;
        }
        g[j] = s;
    }
}

extern "C" void kernel_launch(void* const* d_in, const int* in_sizes, int n_in,
                              void* d_out, int out_size, void* d_ws, size_t ws_size,
                              hipStream_t stream)
{
    const float* x = (const float*)d_in[0];   // [8192][1024]
    const float* W = (const float*)d_in[1];   // [1024][4096]

    // d_out doubles as scratch until the final GEMM writes it:
    //   [0,16MiB): xh (bf16 x) until b-GEMM, then t ; [16MiB,+16KiB): g
    bf16_t* xh = (bf16_t*)d_out;
    bf16_t* tt = (bf16_t*)d_out;
    float*  gd = (float*)((char*)d_out + 16777216);

    char* ws = (char*)d_ws;                   // 208 MiB total (proven footprint)
    bf16_t* a  = (bf16_t*)(ws);               //  64 MiB [8192][4096]
    bf16_t* bb = (bf16_t*)(ws + 67108864);    //  64 MiB [8192][4096]
    bf16_t* u  = (bf16_t*)(ws + 134217728);   //  64 MiB [8192][4096]
    bf16_t* Wh = (bf16_t*)(ws + 201326592);   //   8 MiB [1024][4096]
    bf16_t* WT = (bf16_t*)(ws + 209715200);   //   8 MiB [4096][1024]

    cast_x_kernel<<<8388608 / 256, 256, 0, stream>>>(x, xh, 8388608);
    prep_w_kernel<<<4194304 / 256, 256, 0, stream>>>(W, Wh, WT);
    prep_g_kernel<<<16, 256, 0, stream>>>(W, gd);

    // b = x@W ; u1 = 0.1b ; a1 = relu(u1-0.1).  A=xh, Bt=WT, N=4096, K=1024, BM=256
    gemm_bt<MODE_B, 256><<<dim3(32, 32), 512, 0, stream>>>(xh, WT, 4096, 1024,
                                                           nullptr, a, bb, u, nullptr);
    // 9 remaining steps: t = a@W^T (BM=128) ; s = t@W fused u/a update (BM=256)
    for (int s = 0; s < 9; ++s) {
        gemm_bt<MODE_T, 128><<<dim3(8, 64), 256, 0, stream>>>(a, Wh, 1024, 4096,
                                                              nullptr, tt, nullptr, nullptr, nullptr);
        gemm_bt<MODE_STEP2, 256><<<dim3(32, 32), 512, 0, stream>>>(tt, WT, 4096, 1024,
                                                                   nullptr, a, bb, u, gd);
    }
    // out = a@W^T : A=a, Bt=Wh, N=1024, K=4096, fp32 into d_out
    gemm_bt<MODE_OUT, 128><<<dim3(8, 64), 256, 0, stream>>>(a, Wh, 1024, 4096,
                                                            (float*)d_out, nullptr, nullptr, nullptr, nullptr);
}